// Round 3
// baseline (1609.305 us; speedup 1.0000x reference)
//
#include <hip/hip_runtime.h>

typedef short bh8 __attribute__((ext_vector_type(8)));   // 8 bf16 (4 VGPRs) MFMA A/B frag
typedef short s4v __attribute__((ext_vector_type(4)));   // 4 bf16 (8B)
typedef float f4  __attribute__((ext_vector_type(4)));   // MFMA C/D frag

#define MFMA16(A,B,C) __builtin_amdgcn_mfma_f32_16x16x32_bf16((A),(B),(C),0,0,0)

__device__ __forceinline__ short f2bf(float x){          // RNE float->bf16 bits
    unsigned u = __float_as_uint(x);
    u += 0x7fff + ((u >> 16) & 1);
    return (short)(u >> 16);
}
__device__ __forceinline__ float bf2f(short s){
    return __uint_as_float(((unsigned)(unsigned short)s) << 16);
}

// One block per (b,h). 256 threads = 4 waves. All GEMMs on 16x16x32 bf16 MFMA.
// Q,K path uses hi/lo bf16 split (3-term MFMA) for fp32-grade S (softmax-safe).
__global__ __launch_bounds__(256, 2)
void fused_ca_mfma(const float* __restrict__ hid, const float* __restrict__ ctx,
                   const float* __restrict__ qdw, const float* __restrict__ qdb,
                   const float* __restrict__ qpw, const float* __restrict__ qpb,
                   const float* __restrict__ kdw, const float* __restrict__ kdb,
                   const float* __restrict__ kpw, const float* __restrict__ kpb,
                   const float* __restrict__ vdw, const float* __restrict__ vdb,
                   const float* __restrict__ vpw, const float* __restrict__ vpb,
                   float* __restrict__ out)
{
    // ---- LDS layout (61 KB -> 2 blocks/CU) ----
    __shared__ __align__(16) char smem[62464];
    short* stageH = (short*)(smem);            // [32 w][72 c] conv^T hi  4608 B
    short* stageL = (short*)(smem +  4608);    // [32 w][72 c] conv^T lo  4608 B
    short* sQh    = (short*)(smem +  9216);    // [64 c][40 w]            5120 B
    short* sQl    = (short*)(smem + 14336);
    short* sKh    = (short*)(smem + 19456);
    short* sKl    = (short*)(smem + 24576);
    char*  sVt    = smem + 29696;              // [256 w][64 d] bf16, XOR-swizzled 32768 B
    short* sP     = (short*)(smem +  9216);    // [64 c][72 d] alias over sQ (phase 2 only)

    const int tid = threadIdx.x;
    // XCD swizzle: xcd = bid&7 gets contiguous (b,h) range -> h-halo L2/L3 locality
    const int bid = blockIdx.x;
    const int lin = (bid & 7) * 256 + (bid >> 3);
    const int b   = lin >> 8;
    const int h   = lin & 255;

    const int wv  = tid >> 6;        // wave 0..3
    const int ln  = tid & 63;
    const int l15 = ln & 15;
    const int g   = ln >> 4;         // quad 0..3
    const int wl  = tid & 31;        // conv: w within chunk
    const int g8  = tid >> 5;        // conv: channel-group 0..7

    const float SCALE = 0.35355339059327373f;  // 1/sqrt(8)

    // ---- pointwise-weight A-frags: rows 16*wv+l15, k = s*32+g*8+j ----
    bh8 WqH[2], WqL[2], WkH[2], WkL[2], WvH[2];
    #pragma unroll
    for (int s = 0; s < 2; s++){
        const int rw = (16*wv + l15)*64 + s*32 + g*8;
        #pragma unroll
        for (int j = 0; j < 8; j++){
            float xq = qpw[rw + j]; short hq = f2bf(xq);
            WqH[s][j] = hq; WqL[s][j] = f2bf(xq - bf2f(hq));
            float xk = kpw[rw + j]; short hk = f2bf(xk);
            WkH[s][j] = hk; WkL[s][j] = f2bf(xk - bf2f(hk));
            WvH[s][j] = f2bf(vpw[rw + j]);
        }
    }
    float bq[4], bk[4], bv[4];
    #pragma unroll
    for (int r = 0; r < 4; r++){
        const int o = 16*wv + 4*g + r;
        bq[r] = qpb[o]; bk[r] = kpb[o]; bv[r] = vpb[o];
    }

    // ---- depthwise conv for 8 channels at one w -> stage[w][c] (transposed) ----
    auto conv_pass = [&](const float* __restrict__ src, const float* __restrict__ dwp,
                         const float* __restrict__ dbp, int wg, bool wantLo){
        float o[8];
        #pragma unroll
        for (int i = 0; i < 8; i++){
            const int c = g8*8 + i;
            float acc = dbp[c];
            #pragma unroll
            for (int dy = 0; dy < 3; dy++){
                const int hr = h + dy - 1;
                if (hr < 0 || hr >= 256) continue;
                const float* p  = src + (((size_t)b*64 + c)*256 + hr)*256;
                const float* wt = dwp + c*9 + dy*3;
                float x0 = 0.f, x2 = 0.f;
                if (wg > 0)   x0 = p[wg-1];
                float x1 = p[wg];
                if (wg < 255) x2 = p[wg+1];
                acc += x0*wt[0] + x1*wt[1] + x2*wt[2];
            }
            o[i] = acc;
        }
        bh8 hv, lv;
        #pragma unroll
        for (int i = 0; i < 8; i++){
            short hb = f2bf(o[i]);
            hv[i] = hb;
            lv[i] = f2bf(o[i] - bf2f(hb));
        }
        *(bh8*)(stageH + wl*72 + g8*8) = hv;
        if (wantLo) *(bh8*)(stageL + wl*72 + g8*8) = lv;
    };

    // ---- pointwise GEMM (hi/lo): D[o][w] = sum_c W[o][c]*conv[c][w] + bias ----
    auto pw_hl = [&](const bh8* WH, const bh8* WL, const float* bias4,
                     short* dH, short* dL){
        #pragma unroll
        for (int wi = 0; wi < 2; wi++){
            f4 acc;
            #pragma unroll
            for (int r = 0; r < 4; r++) acc[r] = bias4[r];
            #pragma unroll
            for (int s = 0; s < 2; s++){
                bh8 Bh = *(const bh8*)(stageH + (wi*16 + l15)*72 + s*32 + g*8);
                bh8 Bl = *(const bh8*)(stageL + (wi*16 + l15)*72 + s*32 + g*8);
                acc = MFMA16(WH[s], Bh, acc);
                acc = MFMA16(WH[s], Bl, acc);
                acc = MFMA16(WL[s], Bh, acc);
            }
            #pragma unroll
            for (int r = 0; r < 4; r++){
                const int o = 16*wv + 4*g + r;
                short hb = f2bf(acc[r]);
                dH[o*40 + wi*16 + l15] = hb;
                dL[o*40 + wi*16 + l15] = f2bf(acc[r] - bf2f(hb));
            }
        }
    };

    // ---- scores accumulator: wave wv owns S rows 16wv..16wv+15, 4 col-tiles ----
    f4 Sacc[4];
    #pragma unroll
    for (int di = 0; di < 4; di++)
        #pragma unroll
        for (int r = 0; r < 4; r++) Sacc[di][r] = 0.f;

    // ================= phase 1: 8 chunks of 32 w =================
    for (int ck = 0; ck < 8; ck++){
        const int wg = ck*32 + wl;

        __syncthreads();                               // prev readers of stage/sQ/sK done
        conv_pass(hid, qdw, qdb, wg, true);
        __syncthreads();
        pw_hl(WqH, WqL, bq, sQh, sQl);
        __syncthreads();                               // pw-q stage reads done
        conv_pass(ctx, kdw, kdb, wg, true);
        __syncthreads();
        pw_hl(WkH, WkL, bk, sKh, sKl);
        __syncthreads();                               // pw-k stage reads done, sK visible
        conv_pass(ctx, vdw, vdb, wg, false);           // ctx rows re-read -> L1/L2 hit
        __syncthreads();

        // pw-v -> sVt (single bf16), XOR-swizzled [w][d]
        #pragma unroll
        for (int wi = 0; wi < 2; wi++){
            f4 acc;
            #pragma unroll
            for (int r = 0; r < 4; r++) acc[r] = bv[r];
            #pragma unroll
            for (int s = 0; s < 2; s++){
                bh8 Bh = *(const bh8*)(stageH + (wi*16 + l15)*72 + s*32 + g*8);
                acc = MFMA16(WvH[s], Bh, acc);
            }
            const int w     = ck*32 + wi*16 + l15;
            const int dbase = 16*wv + 4*g;
            s4v pk;
            #pragma unroll
            for (int r = 0; r < 4; r++) pk[r] = f2bf(acc[r]);
            *(s4v*)(sVt + w*128 + (((dbase>>3) ^ (w&7))<<4) + (dbase&7)*2) = pk;
        }

        // S += q k^T for this chunk (3-term hi/lo)
        {
            bh8 qh = *(const bh8*)(sQh + (16*wv + l15)*40 + g*8);
            bh8 ql = *(const bh8*)(sQl + (16*wv + l15)*40 + g*8);
            #pragma unroll
            for (int di = 0; di < 4; di++){
                bh8 kh = *(const bh8*)(sKh + (di*16 + l15)*40 + g*8);
                bh8 kl = *(const bh8*)(sKl + (di*16 + l15)*40 + g*8);
                Sacc[di] = MFMA16(qh, kh, Sacc[di]);
                Sacc[di] = MFMA16(qh, kl, Sacc[di]);
                Sacc[di] = MFMA16(ql, kh, Sacc[di]);
            }
        }
    }

    __syncthreads();   // all S reads of sQ/sK done before sP (alias) is written

    // ================= softmax over d, in-register =================
    // lane's rows: c = 16wv + 4g + r; cols: d = di*16 + l15
    {
        float mx[4], sm[4];
        #pragma unroll
        for (int r = 0; r < 4; r++){
            mx[r] = -1e30f;
            #pragma unroll
            for (int di = 0; di < 4; di++) mx[r] = fmaxf(mx[r], Sacc[di][r]);
        }
        #pragma unroll
        for (int m = 1; m <= 8; m <<= 1)
            #pragma unroll
            for (int r = 0; r < 4; r++) mx[r] = fmaxf(mx[r], __shfl_xor(mx[r], m));
        float e[4][4];
        #pragma unroll
        for (int r = 0; r < 4; r++) sm[r] = 0.f;
        #pragma unroll
        for (int di = 0; di < 4; di++)
            #pragma unroll
            for (int r = 0; r < 4; r++){
                e[di][r] = __expf((Sacc[di][r] - mx[r]) * SCALE);
                sm[r] += e[di][r];
            }
        #pragma unroll
        for (int m = 1; m <= 8; m <<= 1)
            #pragma unroll
            for (int r = 0; r < 4; r++) sm[r] += __shfl_xor(sm[r], m);
        #pragma unroll
        for (int r = 0; r < 4; r++){
            const float inv = 1.0f / sm[r];
            const int c = 16*wv + 4*g + r;
            #pragma unroll
            for (int di = 0; di < 4; di++)
                sP[c*72 + di*16 + l15] = f2bf(e[di][r] * inv);
        }
    }
    __syncthreads();

    // ================= phase 2: O = P V, from sP + sVt =================
    for (int ck = 0; ck < 8; ck++){
        bh8 A0 = *(const bh8*)(sP + (16*wv + l15)*72 +  0 + g*8);
        bh8 A1 = *(const bh8*)(sP + (16*wv + l15)*72 + 32 + g*8);
        #pragma unroll
        for (int wi = 0; wi < 2; wi++){
            const int w = ck*32 + wi*16 + l15;
            f4 O;
            #pragma unroll
            for (int r = 0; r < 4; r++) O[r] = 0.f;
            bh8 B0 = *(const bh8*)(sVt + w*128 + (((0 + g) ^ (w&7))<<4));
            bh8 B1 = *(const bh8*)(sVt + w*128 + (((4 + g) ^ (w&7))<<4));
            O = MFMA16(A0, B0, O);
            O = MFMA16(A1, B1, O);
            #pragma unroll
            for (int r = 0; r < 4; r++){
                const int c = 16*wv + 4*g + r;
                out[(((size_t)b*64 + c)*256 + h)*256 + w] = O[r];
            }
        }
    }
}

extern "C" void kernel_launch(void* const* d_in, const int* in_sizes, int n_in,
                              void* d_out, int out_size, void* d_ws, size_t ws_size,
                              hipStream_t stream) {
    const float* hid = (const float*)d_in[0];
    const float* ctx = (const float*)d_in[1];
    const float* qdw = (const float*)d_in[2];
    const float* qdb = (const float*)d_in[3];
    const float* qpw = (const float*)d_in[4];
    const float* qpb = (const float*)d_in[5];
    const float* kdw = (const float*)d_in[6];
    const float* kdb = (const float*)d_in[7];
    const float* kpw = (const float*)d_in[8];
    const float* kpb = (const float*)d_in[9];
    const float* vdw = (const float*)d_in[10];
    const float* vdb = (const float*)d_in[11];
    const float* vpw = (const float*)d_in[12];
    const float* vpb = (const float*)d_in[13];
    float* out = (float*)d_out;

    dim3 grid(8 * 256);   // 2048 blocks, one per (b,h)
    dim3 block(256);
    fused_ca_mfma<<<grid, block, 0, stream>>>(hid, ctx, qdw, qdb, qpw, qpb,
                                              kdw, kdb, kpw, kpb, vdw, vdb, vpw, vpb,
                                              out);
}